// Round 2
// baseline (1160.514 us; speedup 1.0000x reference)
//
#include <hip/hip_runtime.h>

typedef unsigned short u16;
typedef short s16x8 __attribute__((ext_vector_type(8)));
typedef float f32x4 __attribute__((ext_vector_type(4)));

__device__ __forceinline__ float bf2f(u16 u) {
  return __uint_as_float(((unsigned)u) << 16);
}
__device__ __forceinline__ u16 f2bf(float f) {
  unsigned x = __float_as_uint(f);
  return (u16)((x + 0x7fffu + ((x >> 16) & 1u)) >> 16);
}

// ---------------------------------------------------------------------------
// Transpose [C=192][16384] (fp32 or bf16 input) -> [16384][192] bf16
// grid (3 c-tiles, 512 p-tiles, 8 b), block 256
// ---------------------------------------------------------------------------
template<bool IN_FP32>
__global__ __launch_bounds__(256) void transpose_k(
    const void* __restrict__ inp, u16* __restrict__ outp,
    long batchStride, int chanOffset)
{
  __shared__ float lds[64][33];
  const int c0 = blockIdx.x * 64, p0 = blockIdx.y * 32, b = blockIdx.z;
  const int t = threadIdx.x;
  {
    const int r = t >> 3, pq = (t & 7) * 4;
    #pragma unroll
    for (int i = 0; i < 2; i++) {
      const int c = r + i * 32;
      const long base = (long)b * batchStride + (long)(chanOffset + c0 + c) * 16384 + p0 + pq;
      if (IN_FP32) {
        const float4 v = *(const float4*)((const float*)inp + base);
        lds[c][pq+0] = v.x; lds[c][pq+1] = v.y; lds[c][pq+2] = v.z; lds[c][pq+3] = v.w;
      } else {
        const u16* s = (const u16*)inp + base;
        lds[c][pq+0] = bf2f(s[0]); lds[c][pq+1] = bf2f(s[1]);
        lds[c][pq+2] = bf2f(s[2]); lds[c][pq+3] = bf2f(s[3]);
      }
    }
  }
  __syncthreads();
  const int p = t >> 3, c8 = (t & 7) * 8;
  union { s16x8 v; u16 u[8]; } pk;
  #pragma unroll
  for (int j = 0; j < 8; j++) pk.u[j] = f2bf(lds[c8 + j][p]);
  *(s16x8*)(outp + ((long)b * 16384 + p0 + p) * 192 + c0 + c8) = pk.v;
}

// ---------------------------------------------------------------------------
// NT GEMM: out[b][m][p] = sum_k A[m][k] * B[(b*16384+p)][k],  K = 192 fixed.
// A: fp32 [M][192] (shared across batches) or bf16 [M][192] per batch.
// BM=64, BN=128, BK=64, 4 waves, mfma_f32_16x16x32_bf16.
// grid (M/64, 1024), block 256
// ---------------------------------------------------------------------------
template<bool A_FP32, bool OUT_BF16>
__global__ __launch_bounds__(256) void gemm_nt(
    const void* __restrict__ Ap, const u16* __restrict__ B,
    void* __restrict__ outp, int M, long aBatchStride)
{
  __shared__ char smem[24576];
  char* const As = smem;          // [64][64] bf16, row 128B, XOR-swizzled 16B blocks
  char* const Bs = smem + 8192;   // [128][64] bf16, row 128B, XOR-swizzled

  const int t = threadIdx.x;
  const int m0 = blockIdx.x * 64;
  const int n0 = blockIdx.y * 128;
  const int b  = n0 >> 14;
  const int p0 = n0 & 16383;
  const int wave = t >> 6, lane = t & 63;
  const int l15 = lane & 15, l4 = lane >> 4;

  f32x4 acc[4][2];
  #pragma unroll
  for (int i = 0; i < 4; i++)
    #pragma unroll
    for (int j = 0; j < 2; j++) acc[i][j] = (f32x4){0.f, 0.f, 0.f, 0.f};

  const u16* const Bbase = B + (long)n0 * 192;
  const int ar = t >> 2, ac0 = (t & 3) * 16;
  const int br = t >> 1, bc0 = (t & 1) * 32;

  for (int kc = 0; kc < 192; kc += 64) {
    // stage A tile [64][64]
    if (A_FP32) {
      const float* src = (const float*)Ap + (long)(m0 + ar) * 192 + kc + ac0;
      #pragma unroll
      for (int i = 0; i < 2; i++) {
        float4 f0 = ((const float4*)src)[2*i];
        float4 f1 = ((const float4*)src)[2*i+1];
        union { s16x8 v; u16 u[8]; } pk;
        pk.u[0]=f2bf(f0.x); pk.u[1]=f2bf(f0.y); pk.u[2]=f2bf(f0.z); pk.u[3]=f2bf(f0.w);
        pk.u[4]=f2bf(f1.x); pk.u[5]=f2bf(f1.y); pk.u[6]=f2bf(f1.z); pk.u[7]=f2bf(f1.w);
        *(s16x8*)(As + ar*128 + ((((ac0>>3)+i) ^ (ar&7)) << 4)) = pk.v;
      }
    } else {
      const u16* src = (const u16*)Ap + (long)b * aBatchStride + (long)(m0 + ar) * 192 + kc + ac0;
      #pragma unroll
      for (int i = 0; i < 2; i++) {
        s16x8 v = *(const s16x8*)(src + i*8);
        *(s16x8*)(As + ar*128 + ((((ac0>>3)+i) ^ (ar&7)) << 4)) = v;
      }
    }
    // stage B tile [128][64]
    {
      const u16* src = Bbase + (long)br * 192 + kc + bc0;
      #pragma unroll
      for (int i = 0; i < 4; i++) {
        s16x8 v = *(const s16x8*)(src + i*8);
        *(s16x8*)(Bs + br*128 + ((((bc0>>3)+i) ^ (br&7)) << 4)) = v;
      }
    }
    __syncthreads();
    #pragma unroll
    for (int kq = 0; kq < 2; kq++) {
      const int kb = kq*4 + l4;   // 16B-block index along k for this lane
      s16x8 af[4], bfr[2];
      #pragma unroll
      for (int mi = 0; mi < 4; mi++) {
        const int row = mi*16 + l15;
        af[mi] = *(const s16x8*)(As + row*128 + ((kb ^ (row&7)) << 4));
      }
      #pragma unroll
      for (int ni = 0; ni < 2; ni++) {
        const int row = wave*32 + ni*16 + l15;
        bfr[ni] = *(const s16x8*)(Bs + row*128 + ((kb ^ (row&7)) << 4));
      }
      #pragma unroll
      for (int mi = 0; mi < 4; mi++)
        #pragma unroll
        for (int ni = 0; ni < 2; ni++)
          acc[mi][ni] = __builtin_amdgcn_mfma_f32_16x16x32_bf16(af[mi], bfr[ni], acc[mi][ni], 0, 0, 0);
    }
    __syncthreads();
  }
  const long outBase = (long)b * M * 16384;
  #pragma unroll
  for (int mi = 0; mi < 4; mi++) {
    #pragma unroll
    for (int ni = 0; ni < 2; ni++) {
      const int col = p0 + wave*32 + ni*16 + l15;
      #pragma unroll
      for (int j = 0; j < 4; j++) {
        const int row = m0 + mi*16 + l4*4 + j;
        const float v = acc[mi][ni][j];
        if (OUT_BF16) ((u16*)outp)[outBase + (long)row * 16384 + col] = f2bf(v);
        else          ((float*)outp)[outBase + (long)row * 16384 + col] = v;
      }
    }
  }
}

// ---------------------------------------------------------------------------
// Depthwise 3x3 conv, padding 1, IN-PLACE on qkv (bf16), fused *feature for
// q/k channels. One block per (channel, batch) owns the full 128x128 plane.
// grid (576, 8), block 256
// ---------------------------------------------------------------------------
__global__ __launch_bounds__(256) void dwconv_k(
    u16* __restrict__ qkv, const float* __restrict__ Wdw,
    const float* __restrict__ feature)
{
  __shared__ u16 lds[130*130];
  const int ch = blockIdx.x, b = blockIdx.y;
  u16* const base = qkv + ((long)b * 576 + ch) * 16384;
  const int t = threadIdx.x;
  for (int idx = t; idx < 16900; idx += 256) {
    const int y = idx / 130, xx = idx - y * 130;
    const int gy = y - 1, gx = xx - 1;
    u16 v = 0;
    if ((unsigned)gy < 128u && (unsigned)gx < 128u) v = base[gy*128 + gx];
    lds[idx] = v;
  }
  float w[9];
  #pragma unroll
  for (int i = 0; i < 9; i++) w[i] = Wdw[ch*9 + i];
  __syncthreads();
  const int y = t >> 1, x0 = (t & 1) * 64;
  const int c = ch < 384 ? (ch < 192 ? ch : ch - 192) : -1;
  const float* frow = (c >= 0) ? feature + ((long)b*192 + c)*16384 + y*128 : nullptr;
  for (int xx = 0; xx < 64; xx++) {
    const int x = x0 + xx;
    float a = 0.f;
    #pragma unroll
    for (int dy = 0; dy < 3; dy++)
      #pragma unroll
      for (int dx = 0; dx < 3; dx++)
        a += w[dy*3+dx] * bf2f(lds[(y+dy)*130 + (x+dx)]);
    if (c >= 0) a *= frow[x];
    base[y*128 + x] = f2bf(a);
  }
}

// ---------------------------------------------------------------------------
// Gram: per (b,h) 48x48 self-product of rows U=[q*f ; k*f] over k-chunk 2048.
// MFMA NT self-GEMM; partial per-block result to Gp[bh][kc][48*48].
// grid (8 kc, 64 bh), block 256 (4 waves)
// ---------------------------------------------------------------------------
__global__ __launch_bounds__(256) void gram_k(
    const u16* __restrict__ qkv, float* __restrict__ Gp)
{
  __shared__ u16 us[48*128];       // rows 256B, XOR-swizzled 16B blocks
  __shared__ float red[4*2304];
  const int kc = blockIdx.x, bh = blockIdx.y;
  const int b = bh >> 3, h = bh & 7;
  const int t = threadIdx.x, wave = t >> 6, lane = t & 63;
  const int l15 = lane & 15, l4 = lane >> 4;
  const u16* const qbase = qkv + ((long)b*576 + h*24) * 16384;
  const u16* const kbase = qkv + ((long)b*576 + 192 + h*24) * 16384;
  char* const usb = (char*)us;

  f32x4 acc[3][3];
  #pragma unroll
  for (int i = 0; i < 3; i++)
    #pragma unroll
    for (int j = 0; j < 3; j++) acc[i][j] = (f32x4){0.f, 0.f, 0.f, 0.f};

  for (int step = 0; step < 16; step++) {
    const int k0 = kc*2048 + step*128;
    #pragma unroll
    for (int i = 0; i < 6; i++) {
      const int idx = t + i*256;        // 0..1535: 48 rows x 32 8B-groups
      const int r = idx >> 5, d4 = idx & 31;
      const u16* src = (r < 24 ? qbase + (long)r*16384
                               : kbase + (long)(r-24)*16384) + k0 + d4*4;
      const int col = d4*4;
      *(uint2*)(usb + r*256 + ((((col>>3) ^ (r&7)) << 4)) + ((col&7)<<1)) =
          *(const uint2*)src;
    }
    __syncthreads();
    {
      const int kb = wave*4 + l4;       // 16B block along k (k = wave*32 + 8*l4)
      s16x8 fr[3];
      #pragma unroll
      for (int g = 0; g < 3; g++) {
        const int row = g*16 + l15;
        fr[g] = *(const s16x8*)(usb + row*256 + ((kb ^ (row&7)) << 4));
      }
      #pragma unroll
      for (int gm = 0; gm < 3; gm++)
        #pragma unroll
        for (int gn = 0; gn < 3; gn++)
          acc[gm][gn] = __builtin_amdgcn_mfma_f32_16x16x32_bf16(fr[gm], fr[gn], acc[gm][gn], 0, 0, 0);
    }
    __syncthreads();
  }
  #pragma unroll
  for (int gm = 0; gm < 3; gm++)
    #pragma unroll
    for (int gn = 0; gn < 3; gn++)
      #pragma unroll
      for (int j = 0; j < 4; j++) {
        const int r = gm*16 + l4*4 + j, s = gn*16 + l15;
        red[wave*2304 + r*48 + s] = acc[gm][gn][j];
      }
  __syncthreads();
  for (int idx = t; idx < 2304; idx += 256) {
    const float sum = red[idx] + red[2304+idx] + red[4608+idx] + red[6912+idx];
    Gp[((long)bh*8 + kc)*2304 + idx] = sum;
  }
}

// ---------------------------------------------------------------------------
// Finalize attention: reduce Gram over kc, normalize, temperature, softmax.
// grid 64 (bh), block 256
// ---------------------------------------------------------------------------
__global__ __launch_bounds__(256) void attnfin_k(
    const float* __restrict__ Gp, const float* __restrict__ temperature,
    float* __restrict__ attn)
{
  __shared__ float cross[576];
  __shared__ float qn[24], kn[24];
  const int bh = blockIdx.x, h = bh & 7;
  const int t = threadIdx.x;
  const float* const g = Gp + (long)bh * 8 * 2304;
  for (int idx = t; idx < 624; idx += 256) {
    float s = 0.f;
    if (idx < 576) {
      const int c = idx / 24, d = idx - c * 24;
      #pragma unroll
      for (int kc = 0; kc < 8; kc++) s += g[kc*2304 + c*48 + 24 + d];
      cross[idx] = s;
    } else {
      const int r = idx - 576;  // 0..47 : diag
      #pragma unroll
      for (int kc = 0; kc < 8; kc++) s += g[kc*2304 + r*48 + r];
      const float nv = fmaxf(sqrtf(s), 1e-12f);
      if (r < 24) qn[r] = nv; else kn[r-24] = nv;
    }
  }
  __syncthreads();
  if (t < 24) {
    const float tmp = temperature[h];
    const float qi = 1.f / qn[t];
    float vals[24];
    float m = -1e30f;
    #pragma unroll
    for (int d = 0; d < 24; d++) {
      const float v = cross[t*24 + d] * qi / kn[d] * tmp;
      vals[d] = v; m = fmaxf(m, v);
    }
    float s = 0.f;
    #pragma unroll
    for (int d = 0; d < 24; d++) { vals[d] = __expf(vals[d] - m); s += vals[d]; }
    const float inv = 1.f / s;
    #pragma unroll
    for (int d = 0; d < 24; d++) attn[(long)bh*576 + t*24 + d] = vals[d] * inv;
  }
}

// ---------------------------------------------------------------------------
// M2[b][o][g] = sum_c Wproj[o][h(g)*24+c] * attn[b][h(g)][c][d(g)]  (bf16 out)
// grid 1152, block 256
// ---------------------------------------------------------------------------
__global__ __launch_bounds__(256) void m2_k(
    const float* __restrict__ attn, const float* __restrict__ Wp,
    u16* __restrict__ M2)
{
  const int gid = blockIdx.x * 256 + threadIdx.x;   // < 294912
  const int g = gid % 192;
  const int rem = gid / 192;
  const int o = rem % 192;
  const int b = rem / 192;
  const int h = g / 24, d = g - h*24;
  const float* a = attn + ((long)(b*8 + h) * 24) * 24 + d;
  const float* w = Wp + (long)o * 192 + h * 24;
  float s = 0.f;
  #pragma unroll
  for (int c = 0; c < 24; c++) s += w[c] * a[c*24];
  M2[gid] = f2bf(s);
}

// ---------------------------------------------------------------------------
extern "C" void kernel_launch(void* const* d_in, const int* in_sizes, int n_in,
                              void* d_out, int out_size, void* d_ws, size_t ws_size,
                              hipStream_t stream) {
  const float* x    = (const float*)d_in[0];
  const float* fe   = (const float*)d_in[1];
  const float* Wqkv = (const float*)d_in[2];
  const float* Wdw  = (const float*)d_in[3];
  const float* Wpr  = (const float*)d_in[4];
  const float* temp = (const float*)d_in[5];

  // workspace layout (vT overlays xT: xT dead after qkv GEMM). ~206.8 MB total.
  char* ws = (char*)d_ws;
  u16*   xT  = (u16*)ws;                          // 50,331,648 B  [b*16384+p][192]
  u16*   vT  = xT;                                // reuse
  u16*   qkv = (u16*)(ws + 50331648L);            // 150,994,944 B [b][576][16384]
  float* Gp  = (float*)(ws + 201326592L);         // 4,718,592 B   [64][8][2304]
  float* attn= (float*)(ws + 206045184L);         // 147,456 B     [64][24][24]  (FIXED size)
  u16*   M2  = (u16*)(ws + 206192640L);           // 589,824 B     [b][192][192]

  transpose_k<true ><<<dim3(3,512,8), 256, 0, stream>>>(x,   xT, 192L*16384, 0);
  gemm_nt<true, true ><<<dim3(9,1024), 256, 0, stream>>>(Wqkv, xT, qkv, 576, 0);
  dwconv_k<<<dim3(576,8), 256, 0, stream>>>(qkv, Wdw, fe);
  transpose_k<false><<<dim3(3,512,8), 256, 0, stream>>>(qkv, vT, 576L*16384, 384);
  gram_k<<<dim3(8,64), 256, 0, stream>>>(qkv, Gp);
  attnfin_k<<<64, 256, 0, stream>>>(Gp, temp, attn);
  m2_k<<<1152, 256, 0, stream>>>(attn, Wpr, M2);
  gemm_nt<false, false><<<dim3(3,1024), 256, 0, stream>>>(M2, vT, d_out, 192, 36864L);
}

// Round 3
// 323.798 us; speedup vs baseline: 3.5841x; 3.5841x over previous
//
#include <hip/hip_runtime.h>

typedef unsigned short u16;
typedef short s16x8 __attribute__((ext_vector_type(8)));
typedef float f32x4 __attribute__((ext_vector_type(4)));

__device__ __forceinline__ float bf2f(u16 u) {
  return __uint_as_float(((unsigned)u) << 16);
}
__device__ __forceinline__ u16 f2bf(float f) {
  unsigned x = __float_as_uint(f);
  return (u16)((x + 0x7fffu + ((x >> 16) & 1u)) >> 16);
}

// ---------------------------------------------------------------------------
// Transpose [C=192][16384] (fp32 or bf16 input) -> [16384][192] bf16
// grid (3 c-tiles, 512 p-tiles, 8 b), block 256
// ---------------------------------------------------------------------------
template<bool IN_FP32>
__global__ __launch_bounds__(256) void transpose_k(
    const void* __restrict__ inp, u16* __restrict__ outp,
    long batchStride, int chanOffset)
{
  __shared__ float lds[64][33];
  const int c0 = blockIdx.x * 64, p0 = blockIdx.y * 32, b = blockIdx.z;
  const int t = threadIdx.x;
  {
    const int r = t >> 3, pq = (t & 7) * 4;
    #pragma unroll
    for (int i = 0; i < 2; i++) {
      const int c = r + i * 32;
      const long base = (long)b * batchStride + (long)(chanOffset + c0 + c) * 16384 + p0 + pq;
      if (IN_FP32) {
        const float4 v = *(const float4*)((const float*)inp + base);
        lds[c][pq+0] = v.x; lds[c][pq+1] = v.y; lds[c][pq+2] = v.z; lds[c][pq+3] = v.w;
      } else {
        const u16* s = (const u16*)inp + base;
        lds[c][pq+0] = bf2f(s[0]); lds[c][pq+1] = bf2f(s[1]);
        lds[c][pq+2] = bf2f(s[2]); lds[c][pq+3] = bf2f(s[3]);
      }
    }
  }
  __syncthreads();
  const int p = t >> 3, c8 = (t & 7) * 8;
  union { s16x8 v; u16 u[8]; } pk;
  #pragma unroll
  for (int j = 0; j < 8; j++) pk.u[j] = f2bf(lds[c8 + j][p]);
  *(s16x8*)(outp + ((long)b * 16384 + p0 + p) * 192 + c0 + c8) = pk.v;
}

// ---------------------------------------------------------------------------
// NT GEMM: out[b][m][p] = sum_k A[m][k] * B[(b*16384+p)][k],  K = 192 fixed.
// grid (M/64, 1024), block 256
// ---------------------------------------------------------------------------
template<bool A_FP32, bool OUT_BF16>
__global__ __launch_bounds__(256) void gemm_nt(
    const void* __restrict__ Ap, const u16* __restrict__ B,
    void* __restrict__ outp, int M, long aBatchStride)
{
  __shared__ char smem[24576];
  char* const As = smem;          // [64][64] bf16, row 128B, XOR-swizzled 16B blocks
  char* const Bs = smem + 8192;   // [128][64] bf16, row 128B, XOR-swizzled

  const int t = threadIdx.x;
  const int m0 = blockIdx.x * 64;
  const int n0 = blockIdx.y * 128;
  const int b  = n0 >> 14;
  const int p0 = n0 & 16383;
  const int wave = t >> 6, lane = t & 63;
  const int l15 = lane & 15, l4 = lane >> 4;

  f32x4 acc[4][2];
  #pragma unroll
  for (int i = 0; i < 4; i++)
    #pragma unroll
    for (int j = 0; j < 2; j++) acc[i][j] = (f32x4){0.f, 0.f, 0.f, 0.f};

  const u16* const Bbase = B + (long)n0 * 192;
  const int ar = t >> 2, ac0 = (t & 3) * 16;
  const int br = t >> 1, bc0 = (t & 1) * 32;

  for (int kc = 0; kc < 192; kc += 64) {
    if (A_FP32) {
      const float* src = (const float*)Ap + (long)(m0 + ar) * 192 + kc + ac0;
      #pragma unroll
      for (int i = 0; i < 2; i++) {
        float4 f0 = ((const float4*)src)[2*i];
        float4 f1 = ((const float4*)src)[2*i+1];
        union { s16x8 v; u16 u[8]; } pk;
        pk.u[0]=f2bf(f0.x); pk.u[1]=f2bf(f0.y); pk.u[2]=f2bf(f0.z); pk.u[3]=f2bf(f0.w);
        pk.u[4]=f2bf(f1.x); pk.u[5]=f2bf(f1.y); pk.u[6]=f2bf(f1.z); pk.u[7]=f2bf(f1.w);
        *(s16x8*)(As + ar*128 + ((((ac0>>3)+i) ^ (ar&7)) << 4)) = pk.v;
      }
    } else {
      const u16* src = (const u16*)Ap + (long)b * aBatchStride + (long)(m0 + ar) * 192 + kc + ac0;
      #pragma unroll
      for (int i = 0; i < 2; i++) {
        s16x8 v = *(const s16x8*)(src + i*8);
        *(s16x8*)(As + ar*128 + ((((ac0>>3)+i) ^ (ar&7)) << 4)) = v;
      }
    }
    {
      const u16* src = Bbase + (long)br * 192 + kc + bc0;
      #pragma unroll
      for (int i = 0; i < 4; i++) {
        s16x8 v = *(const s16x8*)(src + i*8);
        *(s16x8*)(Bs + br*128 + ((((bc0>>3)+i) ^ (br&7)) << 4)) = v;
      }
    }
    __syncthreads();
    #pragma unroll
    for (int kq = 0; kq < 2; kq++) {
      const int kb = kq*4 + l4;
      s16x8 af[4], bfr[2];
      #pragma unroll
      for (int mi = 0; mi < 4; mi++) {
        const int row = mi*16 + l15;
        af[mi] = *(const s16x8*)(As + row*128 + ((kb ^ (row&7)) << 4));
      }
      #pragma unroll
      for (int ni = 0; ni < 2; ni++) {
        const int row = wave*32 + ni*16 + l15;
        bfr[ni] = *(const s16x8*)(Bs + row*128 + ((kb ^ (row&7)) << 4));
      }
      #pragma unroll
      for (int mi = 0; mi < 4; mi++)
        #pragma unroll
        for (int ni = 0; ni < 2; ni++)
          acc[mi][ni] = __builtin_amdgcn_mfma_f32_16x16x32_bf16(af[mi], bfr[ni], acc[mi][ni], 0, 0, 0);
    }
    __syncthreads();
  }
  const long outBase = (long)b * M * 16384;
  #pragma unroll
  for (int mi = 0; mi < 4; mi++) {
    #pragma unroll
    for (int ni = 0; ni < 2; ni++) {
      const int col = p0 + wave*32 + ni*16 + l15;
      #pragma unroll
      for (int j = 0; j < 4; j++) {
        const int row = m0 + mi*16 + l4*4 + j;
        const float v = acc[mi][ni][j];
        if (OUT_BF16) ((u16*)outp)[outBase + (long)row * 16384 + col] = f2bf(v);
        else          ((float*)outp)[outBase + (long)row * 16384 + col] = v;
      }
    }
  }
}

// ---------------------------------------------------------------------------
// Depthwise 3x3 conv, padding 1, IN-PLACE on qkv (bf16), fused *feature for
// q/k channels. One block per (channel, batch) owns the full 128x128 plane.
// Lane-contiguous vector I/O: each thread handles 8 consecutive x (16B);
// a wave covers 4 full rows = 1KB contiguous per instruction.
// LDS [130][132] bf16: dword stride 66 -> banks (2y+4x)%32, 2-way (free).
// grid (576, 8), block 256
// ---------------------------------------------------------------------------
__global__ __launch_bounds__(256) void dwconv_k(
    u16* __restrict__ qkv, const float* __restrict__ Wdw,
    const float* __restrict__ feature)
{
  __shared__ u16 lds[130*132];
  const int ch = blockIdx.x, b = blockIdx.y;
  u16* const base = qkv + ((long)b * 576 + ch) * 16384;
  const int t = threadIdx.x;

  // zero all of LDS (halo included): 34320 B = 2145 uint4
  {
    uint4* z = (uint4*)lds;
    #pragma unroll
    for (int i = 0; i < 9; i++) {
      const int idx = t + i*256;
      if (idx < 2145) z[idx] = (uint4){0,0,0,0};
    }
  }
  float w[9];
  #pragma unroll
  for (int i = 0; i < 9; i++) w[i] = Wdw[ch*9 + i];
  __syncthreads();

  // fill interior [1..128][1..128]
  #pragma unroll
  for (int i = 0; i < 8; i++) {
    const int p = t + i*256;            // 0..2047 chunks of 8 u16
    const int y = p >> 4, x = (p & 15) * 8;
    union { uint4 v; u16 u[8]; } ld;
    ld.v = *(const uint4*)(base + y*128 + x);
    u16* d = &lds[(y+1)*132 + x + 1];
    #pragma unroll
    for (int k = 0; k < 8; k++) d[k] = ld.u[k];
  }
  __syncthreads();

  const int c = ch < 384 ? (ch < 192 ? ch : ch - 192) : -1;
  const float* fbase = (c >= 0) ? feature + ((long)b*192 + c)*16384 : nullptr;

  #pragma unroll
  for (int i = 0; i < 8; i++) {
    const int p = t + i*256;
    const int y = p >> 4, x = (p & 15) * 8;
    float r[3][10];
    #pragma unroll
    for (int dy = 0; dy < 3; dy++)
      #pragma unroll
      for (int j = 0; j < 10; j++)
        r[dy][j] = bf2f(lds[(y+dy)*132 + x + j]);
    float acc[8];
    #pragma unroll
    for (int xx = 0; xx < 8; xx++)
      acc[xx] = w[0]*r[0][xx] + w[1]*r[0][xx+1] + w[2]*r[0][xx+2]
              + w[3]*r[1][xx] + w[4]*r[1][xx+1] + w[5]*r[1][xx+2]
              + w[6]*r[2][xx] + w[7]*r[2][xx+1] + w[8]*r[2][xx+2];
    if (c >= 0) {
      const float4 f0 = *(const float4*)(fbase + y*128 + x);
      const float4 f1 = *(const float4*)(fbase + y*128 + x + 4);
      acc[0]*=f0.x; acc[1]*=f0.y; acc[2]*=f0.z; acc[3]*=f0.w;
      acc[4]*=f1.x; acc[5]*=f1.y; acc[6]*=f1.z; acc[7]*=f1.w;
    }
    union { uint4 v; u16 u[8]; } st;
    #pragma unroll
    for (int xx = 0; xx < 8; xx++) st.u[xx] = f2bf(acc[xx]);
    *(uint4*)(base + y*128 + x) = st.v;
  }
}

// ---------------------------------------------------------------------------
// Gram: per (b,h) 48x48 self-product of rows U=[q*f ; k*f] over k-chunk 2048.
// grid (8 kc, 64 bh), block 256 (4 waves)
// ---------------------------------------------------------------------------
__global__ __launch_bounds__(256) void gram_k(
    const u16* __restrict__ qkv, float* __restrict__ Gp)
{
  __shared__ u16 us[48*128];
  __shared__ float red[4*2304];
  const int kc = blockIdx.x, bh = blockIdx.y;
  const int b = bh >> 3, h = bh & 7;
  const int t = threadIdx.x, wave = t >> 6, lane = t & 63;
  const int l15 = lane & 15, l4 = lane >> 4;
  const u16* const qbase = qkv + ((long)b*576 + h*24) * 16384;
  const u16* const kbase = qkv + ((long)b*576 + 192 + h*24) * 16384;
  char* const usb = (char*)us;

  f32x4 acc[3][3];
  #pragma unroll
  for (int i = 0; i < 3; i++)
    #pragma unroll
    for (int j = 0; j < 3; j++) acc[i][j] = (f32x4){0.f, 0.f, 0.f, 0.f};

  for (int step = 0; step < 16; step++) {
    const int k0 = kc*2048 + step*128;
    #pragma unroll
    for (int i = 0; i < 6; i++) {
      const int idx = t + i*256;
      const int r = idx >> 5, d4 = idx & 31;
      const u16* src = (r < 24 ? qbase + (long)r*16384
                               : kbase + (long)(r-24)*16384) + k0 + d4*4;
      const int col = d4*4;
      *(uint2*)(usb + r*256 + ((((col>>3) ^ (r&7)) << 4)) + ((col&7)<<1)) =
          *(const uint2*)src;
    }
    __syncthreads();
    {
      const int kb = wave*4 + l4;
      s16x8 fr[3];
      #pragma unroll
      for (int g = 0; g < 3; g++) {
        const int row = g*16 + l15;
        fr[g] = *(const s16x8*)(usb + row*256 + ((kb ^ (row&7)) << 4));
      }
      #pragma unroll
      for (int gm = 0; gm < 3; gm++)
        #pragma unroll
        for (int gn = 0; gn < 3; gn++)
          acc[gm][gn] = __builtin_amdgcn_mfma_f32_16x16x32_bf16(fr[gm], fr[gn], acc[gm][gn], 0, 0, 0);
    }
    __syncthreads();
  }
  #pragma unroll
  for (int gm = 0; gm < 3; gm++)
    #pragma unroll
    for (int gn = 0; gn < 3; gn++)
      #pragma unroll
      for (int j = 0; j < 4; j++) {
        const int r = gm*16 + l4*4 + j, s = gn*16 + l15;
        red[wave*2304 + r*48 + s] = acc[gm][gn][j];
      }
  __syncthreads();
  for (int idx = t; idx < 2304; idx += 256) {
    const float sum = red[idx] + red[2304+idx] + red[4608+idx] + red[6912+idx];
    Gp[((long)bh*8 + kc)*2304 + idx] = sum;
  }
}

// ---------------------------------------------------------------------------
// Finalize attention: reduce Gram over kc, normalize, temperature, softmax.
// grid 64 (bh), block 256
// ---------------------------------------------------------------------------
__global__ __launch_bounds__(256) void attnfin_k(
    const float* __restrict__ Gp, const float* __restrict__ temperature,
    float* __restrict__ attn)
{
  __shared__ float cross[576];
  __shared__ float qn[24], kn[24];
  const int bh = blockIdx.x, h = bh & 7;
  const int t = threadIdx.x;
  const float* const g = Gp + (long)bh * 8 * 2304;
  for (int idx = t; idx < 624; idx += 256) {
    float s = 0.f;
    if (idx < 576) {
      const int c = idx / 24, d = idx - c * 24;
      #pragma unroll
      for (int kc = 0; kc < 8; kc++) s += g[kc*2304 + c*48 + 24 + d];
      cross[idx] = s;
    } else {
      const int r = idx - 576;
      #pragma unroll
      for (int kc = 0; kc < 8; kc++) s += g[kc*2304 + r*48 + r];
      const float nv = fmaxf(sqrtf(s), 1e-12f);
      if (r < 24) qn[r] = nv; else kn[r-24] = nv;
    }
  }
  __syncthreads();
  if (t < 24) {
    const float tmp = temperature[h];
    const float qi = 1.f / qn[t];
    float vals[24];
    float m = -1e30f;
    #pragma unroll
    for (int d = 0; d < 24; d++) {
      const float v = cross[t*24 + d] * qi / kn[d] * tmp;
      vals[d] = v; m = fmaxf(m, v);
    }
    float s = 0.f;
    #pragma unroll
    for (int d = 0; d < 24; d++) { vals[d] = __expf(vals[d] - m); s += vals[d]; }
    const float inv = 1.f / s;
    #pragma unroll
    for (int d = 0; d < 24; d++) attn[(long)bh*576 + t*24 + d] = vals[d] * inv;
  }
}

// ---------------------------------------------------------------------------
// M2[b][o][g] = sum_c Wproj[o][h(g)*24+c] * attn[b][h(g)][c][d(g)]  (bf16 out)
// grid 1152, block 256
// ---------------------------------------------------------------------------
__global__ __launch_bounds__(256) void m2_k(
    const float* __restrict__ attn, const float* __restrict__ Wp,
    u16* __restrict__ M2)
{
  const int gid = blockIdx.x * 256 + threadIdx.x;
  const int g = gid % 192;
  const int rem = gid / 192;
  const int o = rem % 192;
  const int b = rem / 192;
  const int h = g / 24, d = g - h*24;
  const float* a = attn + ((long)(b*8 + h) * 24) * 24 + d;
  const float* w = Wp + (long)o * 192 + h * 24;
  float s = 0.f;
  #pragma unroll
  for (int c = 0; c < 24; c++) s += w[c] * a[c*24];
  M2[gid] = f2bf(s);
}

// ---------------------------------------------------------------------------
extern "C" void kernel_launch(void* const* d_in, const int* in_sizes, int n_in,
                              void* d_out, int out_size, void* d_ws, size_t ws_size,
                              hipStream_t stream) {
  const float* x    = (const float*)d_in[0];
  const float* fe   = (const float*)d_in[1];
  const float* Wqkv = (const float*)d_in[2];
  const float* Wdw  = (const float*)d_in[3];
  const float* Wpr  = (const float*)d_in[4];
  const float* temp = (const float*)d_in[5];

  char* ws = (char*)d_ws;
  u16*   xT  = (u16*)ws;                          // 50,331,648 B  [b*16384+p][192]
  u16*   vT  = xT;                                // reuse (xT dead after qkv GEMM)
  u16*   qkv = (u16*)(ws + 50331648L);            // 150,994,944 B [b][576][16384]
  float* Gp  = (float*)(ws + 201326592L);         // 4,718,592 B   [64][8][2304]
  float* attn= (float*)(ws + 206045184L);         // 147,456 B     [64][24][24]
  u16*   M2  = (u16*)(ws + 206192640L);           // 589,824 B     [b][192][192]

  transpose_k<true ><<<dim3(3,512,8), 256, 0, stream>>>(x,   xT, 192L*16384, 0);
  gemm_nt<true, true ><<<dim3(9,1024), 256, 0, stream>>>(Wqkv, xT, qkv, 576, 0);
  dwconv_k<<<dim3(576,8), 256, 0, stream>>>(qkv, Wdw, fe);
  transpose_k<false><<<dim3(3,512,8), 256, 0, stream>>>(qkv, vT, 576L*16384, 384);
  gram_k<<<dim3(8,64), 256, 0, stream>>>(qkv, Gp);
  attnfin_k<<<64, 256, 0, stream>>>(Gp, temp, attn);
  m2_k<<<1152, 256, 0, stream>>>(attn, Wpr, M2);
  gemm_nt<false, false><<<dim3(3,1024), 256, 0, stream>>>(M2, vT, d_out, 192, 36864L);
}

// Round 4
// 280.089 us; speedup vs baseline: 4.1434x; 1.1561x over previous
//
#include <hip/hip_runtime.h>

typedef unsigned short u16;
typedef short s16x8 __attribute__((ext_vector_type(8)));
typedef float f32x4 __attribute__((ext_vector_type(4)));

__device__ __forceinline__ float bf2f(u16 u) {
  return __uint_as_float(((unsigned)u) << 16);
}
__device__ __forceinline__ u16 f2bf(float f) {
  unsigned x = __float_as_uint(f);
  return (u16)((x + 0x7fffu + ((x >> 16) & 1u)) >> 16);
}

// ---------------------------------------------------------------------------
// Transpose [C=192][16384] (fp32 or bf16 input) -> [16384][192] bf16
// grid (3 c-tiles, 512 p-tiles, 8 b), block 256
// ---------------------------------------------------------------------------
template<bool IN_FP32>
__global__ __launch_bounds__(256) void transpose_k(
    const void* __restrict__ inp, u16* __restrict__ outp,
    long batchStride, int chanOffset)
{
  __shared__ float lds[64][33];
  const int c0 = blockIdx.x * 64, p0 = blockIdx.y * 32, b = blockIdx.z;
  const int t = threadIdx.x;
  {
    const int r = t >> 3, pq = (t & 7) * 4;
    #pragma unroll
    for (int i = 0; i < 2; i++) {
      const int c = r + i * 32;
      const long base = (long)b * batchStride + (long)(chanOffset + c0 + c) * 16384 + p0 + pq;
      if (IN_FP32) {
        const float4 v = *(const float4*)((const float*)inp + base);
        lds[c][pq+0] = v.x; lds[c][pq+1] = v.y; lds[c][pq+2] = v.z; lds[c][pq+3] = v.w;
      } else {
        const u16* s = (const u16*)inp + base;
        lds[c][pq+0] = bf2f(s[0]); lds[c][pq+1] = bf2f(s[1]);
        lds[c][pq+2] = bf2f(s[2]); lds[c][pq+3] = bf2f(s[3]);
      }
    }
  }
  __syncthreads();
  const int p = t >> 3, c8 = (t & 7) * 8;
  union { s16x8 v; u16 u[8]; } pk;
  #pragma unroll
  for (int j = 0; j < 8; j++) pk.u[j] = f2bf(lds[c8 + j][p]);
  *(s16x8*)(outp + ((long)b * 16384 + p0 + p) * 192 + c0 + c8) = pk.v;
}

// ---------------------------------------------------------------------------
// Persistent-B NT GEMM: out[b][m][p] = sum_k A[m][k]*B[(b*16384+p)][k], K=192.
// One block per n-tile (128 B-rows). B tile [128][192] staged in LDS ONCE
// (48KB); loop over mTiles m-tiles with A chunk staging [64][64] (8KB).
// Eliminates the multi-m-tile B re-fetch (was 4x HBM over-fetch).
// grid (1024), block 256 (4 waves)
// ---------------------------------------------------------------------------
template<bool A_FP32, bool OUT_BF16>
__global__ __launch_bounds__(256) void gemm_nt(
    const void* __restrict__ Ap, const u16* __restrict__ B,
    void* __restrict__ outp, int mTiles, long aBatchStride)
{
  __shared__ char smem[57344];
  char* const Bs = smem;           // [128][24 x 16B blk], row 384B, XOR-swz
  char* const As = smem + 49152;   // [64][8 x 16B blk],  row 128B, XOR-swz

  const int t = threadIdx.x;
  const int n0 = blockIdx.x * 128;
  const int b  = n0 >> 14;
  const int p0 = n0 & 16383;
  const int wave = t >> 6, lane = t & 63;
  const int l15 = lane & 15, l4 = lane >> 4;

  // stage B tile: 48KB contiguous from B + n0*192
  {
    const uint4* src = (const uint4*)(B + (long)n0 * 192);
    #pragma unroll
    for (int i = 0; i < 12; i++) {
      const int ci = t + i*256;            // 16B chunk, 0..3071
      const int r = ci / 24, cb = ci % 24; // row p, 16B block along k
      const uint4 v = src[ci];
      *(uint4*)(Bs + r*384 + ((cb ^ (r&7)) << 4)) = v;
    }
  }

  const int M = mTiles * 64;
  for (int mt = 0; mt < mTiles; mt++) {
    const int m0 = mt * 64;
    f32x4 acc[4][2];
    #pragma unroll
    for (int i = 0; i < 4; i++)
      #pragma unroll
      for (int j = 0; j < 2; j++) acc[i][j] = (f32x4){0.f, 0.f, 0.f, 0.f};

    for (int kc3 = 0; kc3 < 3; kc3++) {
      if (mt | kc3) __syncthreads();   // protect As from in-flight reads
      // stage A chunk [64 rows][64 cols] at k offset kc3*64
      #pragma unroll
      for (int i = 0; i < 2; i++) {
        const int ci = t + i*256;          // 0..511
        const int r = ci >> 3, cb = ci & 7;
        union { uint4 v; u16 u[8]; } pk;
        if (A_FP32) {
          const float* src = (const float*)Ap + (long)(m0 + r) * 192 + kc3*64 + cb*8;
          const float4 f0 = ((const float4*)src)[0];
          const float4 f1 = ((const float4*)src)[1];
          pk.u[0]=f2bf(f0.x); pk.u[1]=f2bf(f0.y); pk.u[2]=f2bf(f0.z); pk.u[3]=f2bf(f0.w);
          pk.u[4]=f2bf(f1.x); pk.u[5]=f2bf(f1.y); pk.u[6]=f2bf(f1.z); pk.u[7]=f2bf(f1.w);
        } else {
          pk.v = *(const uint4*)((const u16*)Ap + (long)b * aBatchStride
                                 + (long)(m0 + r) * 192 + kc3*64 + cb*8);
        }
        *(uint4*)(As + r*128 + ((cb ^ (r&7)) << 4)) = pk.v;
      }
      __syncthreads();
      #pragma unroll
      for (int kq = 0; kq < 2; kq++) {
        const int kbA = kq*4 + l4;
        const int kbB = kc3*8 + kq*4 + l4;
        s16x8 af[4], bfr[2];
        #pragma unroll
        for (int mi = 0; mi < 4; mi++) {
          const int row = mi*16 + l15;
          af[mi] = *(const s16x8*)(As + row*128 + ((kbA ^ (row&7)) << 4));
        }
        #pragma unroll
        for (int ni = 0; ni < 2; ni++) {
          const int row = wave*32 + ni*16 + l15;
          bfr[ni] = *(const s16x8*)(Bs + row*384 + ((kbB ^ (row&7)) << 4));
        }
        #pragma unroll
        for (int mi = 0; mi < 4; mi++)
          #pragma unroll
          for (int ni = 0; ni < 2; ni++)
            acc[mi][ni] = __builtin_amdgcn_mfma_f32_16x16x32_bf16(af[mi], bfr[ni], acc[mi][ni], 0, 0, 0);
      }
    }
    // epilogue for this m-tile
    const long outBase = (long)b * M * 16384;
    #pragma unroll
    for (int mi = 0; mi < 4; mi++) {
      #pragma unroll
      for (int ni = 0; ni < 2; ni++) {
        const int col = p0 + wave*32 + ni*16 + l15;
        #pragma unroll
        for (int j = 0; j < 4; j++) {
          const int row = m0 + mi*16 + l4*4 + j;
          const float v = acc[mi][ni][j];
          if (OUT_BF16) ((u16*)outp)[outBase + (long)row * 16384 + col] = f2bf(v);
          else          ((float*)outp)[outBase + (long)row * 16384 + col] = v;
        }
      }
    }
  }
}

// ---------------------------------------------------------------------------
// Depthwise 3x3 conv, padding 1, IN-PLACE on qkv (bf16). One block per
// (channel, batch); plane staged in LDS [130][132]; 16B lane-contiguous I/O.
// (feature multiply moved into gram_k staging)
// grid (576, 8), block 256
// ---------------------------------------------------------------------------
__global__ __launch_bounds__(256) void dwconv_k(
    u16* __restrict__ qkv, const float* __restrict__ Wdw)
{
  __shared__ u16 lds[130*132];
  const int ch = blockIdx.x, b = blockIdx.y;
  u16* const base = qkv + ((long)b * 576 + ch) * 16384;
  const int t = threadIdx.x;

  {
    uint4* z = (uint4*)lds;
    #pragma unroll
    for (int i = 0; i < 9; i++) {
      const int idx = t + i*256;
      if (idx < 2145) z[idx] = (uint4){0,0,0,0};
    }
  }
  float w[9];
  #pragma unroll
  for (int i = 0; i < 9; i++) w[i] = Wdw[ch*9 + i];
  __syncthreads();

  #pragma unroll
  for (int i = 0; i < 8; i++) {
    const int p = t + i*256;
    const int y = p >> 4, x = (p & 15) * 8;
    union { uint4 v; u16 u[8]; } ld;
    ld.v = *(const uint4*)(base + y*128 + x);
    u16* d = &lds[(y+1)*132 + x + 1];
    #pragma unroll
    for (int k = 0; k < 8; k++) d[k] = ld.u[k];
  }
  __syncthreads();

  #pragma unroll
  for (int i = 0; i < 8; i++) {
    const int p = t + i*256;
    const int y = p >> 4, x = (p & 15) * 8;
    float r[3][10];
    #pragma unroll
    for (int dy = 0; dy < 3; dy++)
      #pragma unroll
      for (int j = 0; j < 10; j++)
        r[dy][j] = bf2f(lds[(y+dy)*132 + x + j]);
    float acc[8];
    #pragma unroll
    for (int xx = 0; xx < 8; xx++)
      acc[xx] = w[0]*r[0][xx] + w[1]*r[0][xx+1] + w[2]*r[0][xx+2]
              + w[3]*r[1][xx] + w[4]*r[1][xx+1] + w[5]*r[1][xx+2]
              + w[6]*r[2][xx] + w[7]*r[2][xx+1] + w[8]*r[2][xx+2];
    union { uint4 v; u16 u[8]; } st;
    #pragma unroll
    for (int xx = 0; xx < 8; xx++) st.u[xx] = f2bf(acc[xx]);
    *(uint4*)(base + y*128 + x) = st.v;
  }
}

// ---------------------------------------------------------------------------
// Gram: per (b,h) 48x48 self-product of rows U=[q*f ; k*f] over k-chunk 2048.
// Feature multiply fused into staging (f read once; q,k rows share one load).
// grid (8 kc, 64 bh), block 256 (4 waves)
// ---------------------------------------------------------------------------
__global__ __launch_bounds__(256) void gram_k(
    const u16* __restrict__ qkv, const float* __restrict__ feature,
    float* __restrict__ Gp)
{
  __shared__ u16 us[48*128];
  __shared__ float red[4*2304];
  const int kc = blockIdx.x, bh = blockIdx.y;
  const int b = bh >> 3, h = bh & 7;
  const int t = threadIdx.x, wave = t >> 6, lane = t & 63;
  const int l15 = lane & 15, l4 = lane >> 4;
  const u16* const qbase = qkv + ((long)b*576 + h*24) * 16384;
  const u16* const kbase = qkv + ((long)b*576 + 192 + h*24) * 16384;
  const float* const fbase = feature + ((long)b*192 + h*24) * 16384;
  char* const usb = (char*)us;

  f32x4 acc[3][3];
  #pragma unroll
  for (int i = 0; i < 3; i++)
    #pragma unroll
    for (int j = 0; j < 3; j++) acc[i][j] = (f32x4){0.f, 0.f, 0.f, 0.f};

  for (int step = 0; step < 16; step++) {
    const int k0 = kc*2048 + step*128;
    #pragma unroll
    for (int i = 0; i < 3; i++) {
      const int idx = t + i*256;        // 0..767: 24 c-rows x 32 4px-groups
      const int r = idx >> 5, d4 = idx & 31;
      const long po = (long)r*16384 + k0 + d4*4;
      const float4 f4 = *(const float4*)(fbase + po);
      union { uint2 v; u16 u[4]; } uq, uk, oq, ok;
      uq.v = *(const uint2*)(qbase + po);
      uk.v = *(const uint2*)(kbase + po);
      const float fv[4] = {f4.x, f4.y, f4.z, f4.w};
      #pragma unroll
      for (int j = 0; j < 4; j++) {
        oq.u[j] = f2bf(bf2f(uq.u[j]) * fv[j]);
        ok.u[j] = f2bf(bf2f(uk.u[j]) * fv[j]);
      }
      const int col = d4*4;
      const int sub = ((col&7)<<1);
      const int r2 = r + 24;
      *(uint2*)(usb + r *256 + (((col>>3) ^ (r &7)) << 4) + sub) = oq.v;
      *(uint2*)(usb + r2*256 + (((col>>3) ^ (r2&7)) << 4) + sub) = ok.v;
    }
    __syncthreads();
    {
      const int kb = wave*4 + l4;
      s16x8 fr[3];
      #pragma unroll
      for (int g = 0; g < 3; g++) {
        const int row = g*16 + l15;
        fr[g] = *(const s16x8*)(usb + row*256 + ((kb ^ (row&7)) << 4));
      }
      #pragma unroll
      for (int gm = 0; gm < 3; gm++)
        #pragma unroll
        for (int gn = 0; gn < 3; gn++)
          acc[gm][gn] = __builtin_amdgcn_mfma_f32_16x16x32_bf16(fr[gm], fr[gn], acc[gm][gn], 0, 0, 0);
    }
    __syncthreads();
  }
  #pragma unroll
  for (int gm = 0; gm < 3; gm++)
    #pragma unroll
    for (int gn = 0; gn < 3; gn++)
      #pragma unroll
      for (int j = 0; j < 4; j++) {
        const int r = gm*16 + l4*4 + j, s = gn*16 + l15;
        red[wave*2304 + r*48 + s] = acc[gm][gn][j];
      }
  __syncthreads();
  for (int idx = t; idx < 2304; idx += 256) {
    const float sum = red[idx] + red[2304+idx] + red[4608+idx] + red[6912+idx];
    Gp[((long)bh*8 + kc)*2304 + idx] = sum;
  }
}

// ---------------------------------------------------------------------------
// Finalize attention: reduce Gram over kc, normalize, temperature, softmax.
// grid 64 (bh), block 256
// ---------------------------------------------------------------------------
__global__ __launch_bounds__(256) void attnfin_k(
    const float* __restrict__ Gp, const float* __restrict__ temperature,
    float* __restrict__ attn)
{
  __shared__ float cross[576];
  __shared__ float qn[24], kn[24];
  const int bh = blockIdx.x, h = bh & 7;
  const int t = threadIdx.x;
  const float* const g = Gp + (long)bh * 8 * 2304;
  for (int idx = t; idx < 624; idx += 256) {
    float s = 0.f;
    if (idx < 576) {
      const int c = idx / 24, d = idx - c * 24;
      #pragma unroll
      for (int kc = 0; kc < 8; kc++) s += g[kc*2304 + c*48 + 24 + d];
      cross[idx] = s;
    } else {
      const int r = idx - 576;
      #pragma unroll
      for (int kc = 0; kc < 8; kc++) s += g[kc*2304 + r*48 + r];
      const float nv = fmaxf(sqrtf(s), 1e-12f);
      if (r < 24) qn[r] = nv; else kn[r-24] = nv;
    }
  }
  __syncthreads();
  if (t < 24) {
    const float tmp = temperature[h];
    const float qi = 1.f / qn[t];
    float vals[24];
    float m = -1e30f;
    #pragma unroll
    for (int d = 0; d < 24; d++) {
      const float v = cross[t*24 + d] * qi / kn[d] * tmp;
      vals[d] = v; m = fmaxf(m, v);
    }
    float s = 0.f;
    #pragma unroll
    for (int d = 0; d < 24; d++) { vals[d] = __expf(vals[d] - m); s += vals[d]; }
    const float inv = 1.f / s;
    #pragma unroll
    for (int d = 0; d < 24; d++) attn[(long)bh*576 + t*24 + d] = vals[d] * inv;
  }
}

// ---------------------------------------------------------------------------
// M2[b][o][g] = sum_c Wproj[o][h(g)*24+c] * attn[b][h(g)][c][d(g)]  (bf16 out)
// grid 1152, block 256
// ---------------------------------------------------------------------------
__global__ __launch_bounds__(256) void m2_k(
    const float* __restrict__ attn, const float* __restrict__ Wp,
    u16* __restrict__ M2)
{
  const int gid = blockIdx.x * 256 + threadIdx.x;
  const int g = gid % 192;
  const int rem = gid / 192;
  const int o = rem % 192;
  const int b = rem / 192;
  const int h = g / 24, d = g - h*24;
  const float* a = attn + ((long)(b*8 + h) * 24) * 24 + d;
  const float* w = Wp + (long)o * 192 + h * 24;
  float s = 0.f;
  #pragma unroll
  for (int c = 0; c < 24; c++) s += w[c] * a[c*24];
  M2[gid] = f2bf(s);
}

// ---------------------------------------------------------------------------
extern "C" void kernel_launch(void* const* d_in, const int* in_sizes, int n_in,
                              void* d_out, int out_size, void* d_ws, size_t ws_size,
                              hipStream_t stream) {
  const float* x    = (const float*)d_in[0];
  const float* fe   = (const float*)d_in[1];
  const float* Wqkv = (const float*)d_in[2];
  const float* Wdw  = (const float*)d_in[3];
  const float* Wpr  = (const float*)d_in[4];
  const float* temp = (const float*)d_in[5];

  char* ws = (char*)d_ws;
  u16*   xT  = (u16*)ws;                          // 50,331,648 B  [b*16384+p][192]
  u16*   vT  = xT;                                // reuse (xT dead after qkv GEMM)
  u16*   qkv = (u16*)(ws + 50331648L);            // 150,994,944 B [b][576][16384]
  float* Gp  = (float*)(ws + 201326592L);         // 4,718,592 B   [64][8][2304]
  float* attn= (float*)(ws + 206045184L);         // 147,456 B     [64][24][24]
  u16*   M2  = (u16*)(ws + 206192640L);           // 589,824 B     [b][192][192]

  transpose_k<true ><<<dim3(3,512,8), 256, 0, stream>>>(x,   xT, 192L*16384, 0);
  gemm_nt<true, true ><<<1024, 256, 0, stream>>>(Wqkv, xT, qkv, 9, 0);
  dwconv_k<<<dim3(576,8), 256, 0, stream>>>(qkv, Wdw);
  transpose_k<false><<<dim3(3,512,8), 256, 0, stream>>>(qkv, vT, 576L*16384, 384);
  gram_k<<<dim3(8,64), 256, 0, stream>>>(qkv, fe, Gp);
  attnfin_k<<<64, 256, 0, stream>>>(Gp, temp, attn);
  m2_k<<<1152, 256, 0, stream>>>(attn, Wpr, M2);
  gemm_nt<false, false><<<1024, 256, 0, stream>>>(M2, vT, d_out, 3, 36864L);
}